// Round 1
// baseline (322.700 us; speedup 1.0000x reference)
//
#include <hip/hip_runtime.h>

// WeatherLSTM: B=4096 indep. sequences, T=512 sequential steps, H=10, I=O=1.
// Mapping: 4 lanes per batch element (lane t4 = gate type i/f/g/o, 10 rows each),
// 16 elements per wave64, weights held in registers, h/c replicated per lane,
// cross-lane exchange via DPP quad_perm broadcasts (VALU-rate, no LDS).

#define LOG2E 1.4426950408889634f

template<int PAT>
__device__ __forceinline__ float qbcast(float v) {
    // quad_perm broadcast: every lane reads lane (lane&~3)|t, PAT = t*0x55
    return __int_as_float(__builtin_amdgcn_update_dpp(
        0, __float_as_int(v), PAT, 0xF, 0xF, false));
}

__global__ __launch_bounds__(64, 1) void WeatherLSTM_kernel(
    const float* __restrict__ x,     // [B, T, 1]
    const float* __restrict__ W_ih,  // [40, 1]
    const float* __restrict__ W_hh,  // [40, 10]
    const float* __restrict__ b_ih,  // [40]
    const float* __restrict__ b_hh,  // [40]
    const float* __restrict__ W_fc,  // [1, 10]
    const float* __restrict__ b_fc,  // [1]
    float* __restrict__ out,         // [B, 1]
    int T)
{
    const int lane = threadIdx.x;    // block = 64 = 1 wave
    const int quad = lane >> 2;      // 16 elements per wave
    const int t4   = lane & 3;       // gate type: 0=i 1=f 2=g 3=o
    const long e   = (long)blockIdx.x * 16 + quad;

    // Per-lane gate rows g = t4*10 + k, k=0..9 -> all weights in VGPRs (~120)
    float whh[10][10], wih[10], bb[10];
    #pragma unroll
    for (int k = 0; k < 10; ++k) {
        const int g = t4 * 10 + k;
        wih[k] = W_ih[g];
        bb[k]  = b_ih[g] + b_hh[g];
        #pragma unroll
        for (int j = 0; j < 10; ++j)
            whh[k][j] = W_hh[g * 10 + j];
    }

    // Unified activation: sigmoid(v) = rcp(1+exp2(-v*log2e))
    //                     tanh(v)    = 2*rcp(1+exp2(-2v*log2e)) - 1
    const bool  isg = (t4 == 2);
    const float sm  = isg ? (-2.0f * LOG2E) : (-LOG2E);
    const float m2  = isg ? 2.0f : 1.0f;
    const float ac  = isg ? -1.0f : 0.0f;

    float h[10], c[10];
    #pragma unroll
    for (int k = 0; k < 10; ++k) { h[k] = 0.0f; c[k] = 0.0f; }

    const float* xe = x + e * (long)T;
    for (int s0 = 0; s0 < T; s0 += 4) {
        const float4 xv = *reinterpret_cast<const float4*>(xe + s0);
        #pragma unroll
        for (int ss = 0; ss < 4; ++ss) {
            const float xt = (&xv.x)[ss];

            // gate pre-activations + activation (10 independent chains)
            float a[10];
            #pragma unroll
            for (int k = 0; k < 10; ++k) {
                float acc = fmaf(xt, wih[k], bb[k]);
                #pragma unroll
                for (int j = 0; j < 10; ++j)
                    acc = fmaf(h[j], whh[k][j], acc);
                const float ep = __builtin_amdgcn_exp2f(acc * sm);
                const float r  = __builtin_amdgcn_rcpf(1.0f + ep);
                a[k] = fmaf(m2, r, ac);
            }

            // exchange i/f/g/o within the quad, update c/h (replicated)
            #pragma unroll
            for (int k = 0; k < 10; ++k) {
                const float iv = qbcast<0x00>(a[k]);
                const float fv = qbcast<0x55>(a[k]);
                const float gv = qbcast<0xAA>(a[k]);
                const float ov = qbcast<0xFF>(a[k]);
                c[k] = fmaf(fv, c[k], iv * gv);
                const float e2 = __builtin_amdgcn_exp2f(c[k] * (-2.0f * LOG2E));
                const float th = fmaf(2.0f, __builtin_amdgcn_rcpf(1.0f + e2), -1.0f);
                h[k] = ov * th;
            }
        }
    }

    if (t4 == 0) {
        float o = b_fc[0];
        #pragma unroll
        for (int k = 0; k < 10; ++k)
            o = fmaf(h[k], W_fc[k], o);
        out[e] = o;
    }
}

extern "C" void kernel_launch(void* const* d_in, const int* in_sizes, int n_in,
                              void* d_out, int out_size, void* d_ws, size_t ws_size,
                              hipStream_t stream) {
    const float* x    = (const float*)d_in[0];
    const float* W_ih = (const float*)d_in[1];
    const float* W_hh = (const float*)d_in[2];
    const float* b_ih = (const float*)d_in[3];
    const float* b_hh = (const float*)d_in[4];
    const float* W_fc = (const float*)d_in[5];
    const float* b_fc = (const float*)d_in[6];
    float* out = (float*)d_out;

    const int B = out_size;             // 4096
    const int T = in_sizes[0] / B;      // 512

    dim3 grid(B / 16), block(64);       // 16 elements per wave, 1 wave per block
    hipLaunchKernelGGL(WeatherLSTM_kernel, grid, block, 0, stream,
                       x, W_ih, W_hh, b_ih, b_hh, W_fc, b_fc, out, T);
}

// Round 2
// 156.473 us; speedup vs baseline: 2.0623x; 2.0623x over previous
//
#include <hip/hip_runtime.h>

// WeatherLSTM: B=4096 indep. sequences, T=512 steps, H=10 (padded to 12), I=O=1.
// 16 lanes per element: lane = (t = gate type i/f/g/o, q = k-quarter of 3 rows).
// Each lane owns 3 gate rows (weights in VGPRs, ~45 floats). Quad (4 t-lanes)
// exchanges i/f/g/o via DPP quad_perm; each quad owns c/h for its 3 k's
// (replicated over t); full h[12] re-gathered per step via 12 ds_bpermute.
// 4096 elem * 16 lanes = 1024 waves -> 1 wave on every SIMD of the chip.

#define LOG2E 1.4426950408889634f

template<int PAT>
__device__ __forceinline__ float qbcast(float v) {
    // quad_perm broadcast: every lane reads lane (lane&~3)|t, PAT = t*0x55
    return __int_as_float(__builtin_amdgcn_update_dpp(
        0, __float_as_int(v), PAT, 0xF, 0xF, false));
}

__device__ __forceinline__ float bperm(int byteaddr, float v) {
    return __int_as_float(__builtin_amdgcn_ds_bpermute(byteaddr, __float_as_int(v)));
}

__global__ __launch_bounds__(256, 1) void WeatherLSTM_kernel(
    const float* __restrict__ x,     // [B, T, 1]
    const float* __restrict__ W_ih,  // [40, 1]
    const float* __restrict__ W_hh,  // [40, 10]
    const float* __restrict__ b_ih,  // [40]
    const float* __restrict__ b_hh,  // [40]
    const float* __restrict__ W_fc,  // [1, 10]
    const float* __restrict__ b_fc,  // [1]
    float* __restrict__ out,         // [B, 1]
    int T)
{
    const int tid  = threadIdx.x;        // 256 threads = 4 waves = 16 elements
    const int lane = tid & 63;
    const int t4   = lane & 3;           // gate type: 0=i 1=f 2=g 3=o
    const int q4   = (lane >> 2) & 3;    // k-quarter: owns k = q4*3 .. q4*3+2
    const long e   = (long)blockIdx.x * 16 + (tid >> 4);

    // Own 3 gate rows: row g = t4*10 + k, zero-padded for k >= 10 (then the
    // padded c/h stay exactly 0: sigmoid(0)=.5, tanh(0)=0 -> c'=.5c, h'=0).
    float whh[3][12], wih[3], bb[3];
    #pragma unroll
    for (int kk = 0; kk < 3; ++kk) {
        const int k = q4 * 3 + kk;
        const int g = t4 * 10 + k;
        const bool valid = (k < 10);
        wih[kk] = valid ? W_ih[g] : 0.0f;
        bb[kk]  = valid ? (b_ih[g] + b_hh[g]) : 0.0f;
        #pragma unroll
        for (int j = 0; j < 12; ++j)
            whh[kk][j] = (valid && j < 10) ? W_hh[g * 10 + j] : 0.0f;
    }

    // bpermute byte addresses: fetch from quad qj, same gate-type lane, same
    // 16-lane group (wave-local lane bits: group = lane&48, t = lane&3).
    int addrq[4];
    #pragma unroll
    for (int qj = 0; qj < 4; ++qj)
        addrq[qj] = ((lane & 51) | (qj << 2)) << 2;

    // Unified activation: sigmoid(v) = rcp(1+exp2(-v*log2e))
    //                     tanh(v)    = 2*rcp(1+exp2(-2v*log2e)) - 1
    const bool  isg = (t4 == 2);
    const float sm  = isg ? (-2.0f * LOG2E) : (-LOG2E);
    const float m2  = isg ? 2.0f : 1.0f;
    const float ac  = isg ? -1.0f : 0.0f;

    float h[12], c[3], hown[3];
    #pragma unroll
    for (int j = 0; j < 12; ++j) h[j] = 0.0f;
    #pragma unroll
    for (int kk = 0; kk < 3; ++kk) { c[kk] = 0.0f; hown[kk] = 0.0f; }

    const float* xe = x + e * (long)T;
    for (int s0 = 0; s0 < T; s0 += 4) {
        const float4 xv = *reinterpret_cast<const float4*>(xe + s0);
        #pragma unroll
        for (int ss = 0; ss < 4; ++ss) {
            const float xt = (&xv.x)[ss];

            // 3 gate pre-activations + activation (independent chains)
            float a[3];
            #pragma unroll
            for (int kk = 0; kk < 3; ++kk) {
                float acc = fmaf(xt, wih[kk], bb[kk]);
                #pragma unroll
                for (int j = 0; j < 12; ++j)
                    acc = fmaf(h[j], whh[kk][j], acc);
                const float ep = __builtin_amdgcn_exp2f(acc * sm);
                a[kk] = fmaf(m2, __builtin_amdgcn_rcpf(1.0f + ep), ac);
            }

            // quad exchange i/f/g/o; update own c, h (replicated over t-lanes)
            #pragma unroll
            for (int kk = 0; kk < 3; ++kk) {
                const float iv = qbcast<0x00>(a[kk]);
                const float fv = qbcast<0x55>(a[kk]);
                const float gv = qbcast<0xAA>(a[kk]);
                const float ov = qbcast<0xFF>(a[kk]);
                c[kk] = fmaf(fv, c[kk], iv * gv);
                const float e2 = __builtin_amdgcn_exp2f(c[kk] * (-2.0f * LOG2E));
                const float th = fmaf(2.0f, __builtin_amdgcn_rcpf(1.0f + e2), -1.0f);
                hown[kk] = ov * th;
            }

            // all-gather h[12] across the 4 quads (uniform register slots)
            #pragma unroll
            for (int j = 0; j < 12; ++j)
                h[j] = bperm(addrq[j / 3], hown[j % 3]);
        }
    }

    if ((tid & 15) == 0) {
        float o = b_fc[0];
        #pragma unroll
        for (int j = 0; j < 10; ++j)
            o = fmaf(h[j], W_fc[j], o);
        out[e] = o;
    }
}

extern "C" void kernel_launch(void* const* d_in, const int* in_sizes, int n_in,
                              void* d_out, int out_size, void* d_ws, size_t ws_size,
                              hipStream_t stream) {
    const float* x    = (const float*)d_in[0];
    const float* W_ih = (const float*)d_in[1];
    const float* W_hh = (const float*)d_in[2];
    const float* b_ih = (const float*)d_in[3];
    const float* b_hh = (const float*)d_in[4];
    const float* W_fc = (const float*)d_in[5];
    const float* b_fc = (const float*)d_in[6];
    float* out = (float*)d_out;

    const int B = out_size;          // 4096
    const int T = in_sizes[0] / B;   // 512

    dim3 grid(B / 16), block(256);   // 16 elems/block, 256 blocks = 1 per CU
    hipLaunchKernelGGL(WeatherLSTM_kernel, grid, block, 0, stream,
                       x, W_ih, W_hh, b_ih, b_hh, W_fc, b_fc, out, T);
}

// Round 3
// 104.630 us; speedup vs baseline: 3.0842x; 1.4955x over previous
//
#include <hip/hip_runtime.h>

// WeatherLSTM: B=4096 indep. sequences, T=512 steps, H=10, I=O=1.
// Layout R2: lane = hidden unit k (10 active lanes per 16-lane group, 4 groups
// per wave, 16 elements per 256-thread block -> 1024 waves = 1 per SIMD).
// Each lane owns ALL FOUR gate rows for its k -> gates are lane-local (no
// i/f/g/o exchange), c_k/h_k updated once (no replicated tanh), activation
// scale folded into pre-scaled weights. h[10] re-gathered via 10 ds_bpermute.

#define NLOG2E (-1.4426950408889634f)

__device__ __forceinline__ float bperm(int byteaddr, float v) {
    return __int_as_float(__builtin_amdgcn_ds_bpermute(byteaddr, __float_as_int(v)));
}

__global__ __launch_bounds__(256, 1) void WeatherLSTM_kernel(
    const float* __restrict__ x,     // [B, T, 1]
    const float* __restrict__ W_ih,  // [40, 1]
    const float* __restrict__ W_hh,  // [40, 10]
    const float* __restrict__ b_ih,  // [40]
    const float* __restrict__ b_hh,  // [40]
    const float* __restrict__ W_fc,  // [1, 10]
    const float* __restrict__ b_fc,  // [1]
    float* __restrict__ out,         // [B, 1]
    int T)
{
    const int tid  = threadIdx.x;     // 256 = 4 waves = 16 groups of 16 lanes
    const int lane = tid & 63;
    const int k    = tid & 15;        // hidden index; active iff k < 10
    const long e   = (long)blockIdx.x * 16 + (tid >> 4);
    const bool active = (k < 10);

    // Own 4 gate rows (i,f,g,o) for hidden unit k. Pre-scale weights by the
    // activation's exp2 factor: sigmoid(v)=rcp(1+exp2(-v*log2e)),
    // tanh(v)=2*rcp(1+exp2(-2v*log2e))-1 -> row scale -L (gates i,f,o), -2L (g).
    float whh[4][10], wih[4], bb[4];
    #pragma unroll
    for (int t = 0; t < 4; ++t) {
        const float s = (t == 2) ? (2.0f * NLOG2E) : NLOG2E;
        const int g = t * 10 + k;
        wih[t] = active ? W_ih[g] * s : 0.0f;
        bb[t]  = active ? (b_ih[g] + b_hh[g]) * s : 0.0f;
        #pragma unroll
        for (int j = 0; j < 10; ++j)
            whh[t][j] = active ? W_hh[g * 10 + j] * s : 0.0f;
    }
    // Inactive lanes: acc=0 -> i=f=o=.5, g=0 -> c stays 0, h stays 0. Harmless.

    float h[10];
    #pragma unroll
    for (int j = 0; j < 10; ++j) h[j] = 0.0f;
    float c = 0.0f, hown = 0.0f;

    const int base = (lane & 48) << 2;        // group base for bpermute (bytes)
    const float* xe = x + e * (long)T;

    for (int s0 = 0; s0 < T; s0 += 4) {
        const float4 xv = *reinterpret_cast<const float4*>(xe + s0);
        #pragma unroll
        for (int ss = 0; ss < 4; ++ss) {
            const float xt = (&xv.x)[ss];

            // 4 independent gate chains, each dot product split in halves
            float a[4];
            #pragma unroll
            for (int t = 0; t < 4; ++t) {
                float accA = fmaf(xt, wih[t], bb[t]);
                float accB = h[5] * whh[t][5];
                #pragma unroll
                for (int j = 0; j < 5; ++j)
                    accA = fmaf(h[j], whh[t][j], accA);
                #pragma unroll
                for (int j = 6; j < 10; ++j)
                    accB = fmaf(h[j], whh[t][j], accB);
                const float acc = accA + accB;      // already scaled by -L/-2L
                const float r = __builtin_amdgcn_rcpf(
                                    1.0f + __builtin_amdgcn_exp2f(acc));
                a[t] = (t == 2) ? fmaf(2.0f, r, -1.0f) : r;
            }

            // c_k, h_k (single copy per hidden unit)
            c = fmaf(a[1], c, a[0] * a[2]);
            const float e2 = __builtin_amdgcn_exp2f(c * (2.0f * NLOG2E));
            hown = a[3] * fmaf(2.0f, __builtin_amdgcn_rcpf(1.0f + e2), -1.0f);

            // all-gather h[10] across the 16-lane group (offset folds to imm)
            #pragma unroll
            for (int j = 0; j < 10; ++j)
                h[j] = bperm(base + 4 * j, hown);
        }
    }

    if (k == 0) {
        float o = b_fc[0];
        #pragma unroll
        for (int j = 0; j < 10; ++j)
            o = fmaf(h[j], W_fc[j], o);
        out[e] = o;
    }
}

extern "C" void kernel_launch(void* const* d_in, const int* in_sizes, int n_in,
                              void* d_out, int out_size, void* d_ws, size_t ws_size,
                              hipStream_t stream) {
    const float* x    = (const float*)d_in[0];
    const float* W_ih = (const float*)d_in[1];
    const float* W_hh = (const float*)d_in[2];
    const float* b_ih = (const float*)d_in[3];
    const float* b_hh = (const float*)d_in[4];
    const float* W_fc = (const float*)d_in[5];
    const float* b_fc = (const float*)d_in[6];
    float* out = (float*)d_out;

    const int B = out_size;          // 4096
    const int T = in_sizes[0] / B;   // 512

    dim3 grid(B / 16), block(256);   // 16 elems/block, 256 blocks = 1 per CU
    hipLaunchKernelGGL(WeatherLSTM_kernel, grid, block, 0, stream,
                       x, W_ih, W_hh, b_ih, b_hh, W_fc, b_fc, out, T);
}